// Round 16
// baseline (45.248 us; speedup 1.0000x reference)
//
#include <hip/hip_runtime.h>
#include <cstdint>
#include <cstddef>

// NetGrad J = W5 D4 W4 D3 W3 D2 W2 D1 W1, output [B,3,64].
// 32 samples/block, 16 waves (1024 thr) split by COLUMN only (wn=0..15,
// 16-col span, FN=1), 1 block/CU: one full table read per phase (slices
// distinct across waves) AND 4 waves/SIMD so four independent serial
// {B-load -> ds_read -> MFMA} chains interleave in each other's stall
// windows. Each wave carries 6 A-frags (3 o x 2 m) in bwd. Plain LDS
// layout (identity permutation at FN=1). G1..G4 in registers with exact
// fwd->bwd lane mapping. __launch_bounds__(1024,1) caps VGPR at 128 so
// all 16 waves are resident.

typedef _Float16 half_t;
typedef __attribute__((ext_vector_type(8))) _Float16 half8;
typedef __attribute__((ext_vector_type(4))) float f32x4;

#define MFMA16(a, b, c) __builtin_amdgcn_mfma_f32_16x16x32_f16(a, b, c, 0, 0, 0)

constexpr int Bsz = 8192;
constexpr int LDA = 264;          // LDS row stride in halves (528 B)

// ---------------- prep: f16 tables, native + transposed ----------------
__global__ __launch_bounds__(256)
void prep_split(const float* __restrict__ W1, const float* __restrict__ W2,
                const float* __restrict__ W3, const float* __restrict__ W4,
                half_t* W1h, half_t* T1h, half_t* W2h, half_t* T2h,
                half_t* W3h, half_t* T3h, half_t* W4h, half_t* T4h)
{
    __shared__ float tile[32][33];
    const int bid = blockIdx.x;
    const float* src; half_t *sh, *th; int C, bx, by;
    if (bid < 16) {
        src = W1; sh = W1h; th = T1h;
        C = 64; bx = bid & 1; by = bid >> 1;
    } else {
        const int q = bid - 16, j = q >> 6, lo = q & 63;
        bx = lo & 7; by = lo >> 3; C = 256;
        if (j == 0)      { src = W2; sh = W2h; th = T2h; }
        else if (j == 1) { src = W3; sh = W3h; th = T3h; }
        else             { src = W4; sh = W4h; th = T4h; }
    }
    const int R = 256;
    const int tx = threadIdx.x & 31, ty = threadIdx.x >> 5;
    #pragma unroll
    for (int i = 0; i < 32; i += 8) {
        const size_t o = (size_t)(by * 32 + ty + i) * C + bx * 32 + tx;
        const float v = src[o];
        tile[ty + i][tx] = v;
        sh[o] = (half_t)v;
    }
    __syncthreads();
    #pragma unroll
    for (int i = 0; i < 32; i += 8) {
        const float v = tile[tx][ty + i];
        const size_t o = (size_t)(bx * 32 + ty + i) * R + by * 32 + tx;
        th[o] = (half_t)v;
    }
}

// ---------------- fwd layer (K=256): 2 A-frags (m), FN=1 ----------------
template<bool WRITE_H>
__device__ __forceinline__
void fwd_layer(const half_t* __restrict__ Ard, half_t* __restrict__ Awr,
               const half_t* __restrict__ Wh, const float* __restrict__ bias,
               float gout[2][4], int n0w, int lr, int kgrp)
{
    const int col = n0w + lr;
    f32x4 acc[2] = {};
    #pragma unroll
    for (int kc = 0; kc < 8; ++kc) {
        const int ko = kc * 32 + kgrp * 8;
        const half8 b = *(const half8*)(Wh + (size_t)col * 256 + ko);
        half8 a[2];
        #pragma unroll
        for (int m = 0; m < 2; ++m)
            a[m] = *(const half8*)&Ard[(m * 16 + lr) * LDA + ko];
        __builtin_amdgcn_s_setprio(1);
        #pragma unroll
        for (int m = 0; m < 2; ++m)
            acc[m] = MFMA16(a[m], b, acc[m]);
        __builtin_amdgcn_s_setprio(0);
    }
    const float bc = bias[col];
    #pragma unroll
    for (int m = 0; m < 2; ++m)
        #pragma unroll
        for (int r = 0; r < 4; ++r) {
            const float pre = acc[m][r] + bc;
            float g, h;
            if (pre > 0.f) { g = 1.f; h = pre; }
            else           { g = __expf(pre); h = g - 1.f; }
            gout[m][r] = g;
            if constexpr (WRITE_H)
                Awr[(m * 16 + kgrp * 4 + r) * LDA + col] = (half_t)h;
        }
    if constexpr (WRITE_H)
        __syncthreads();
}

// ---------------- bwd mid step: 6 A-frags (3 o x 2 m), FN=1 ----------------
__device__ __forceinline__
void bwd_mid(const half_t* __restrict__ Crd, half_t* __restrict__ Cwr,
             const half_t* __restrict__ Th, const float gpre[2][4],
             int n0w, int lr, int kgrp)
{
    const int col = n0w + lr;
    f32x4 acc[3][2] = {};
    #pragma unroll
    for (int kc = 0; kc < 8; ++kc) {
        const int ko = kc * 32 + kgrp * 8;
        const half8 b = *(const half8*)(Th + (size_t)col * 256 + ko);
        half8 a[3][2];
        #pragma unroll
        for (int o = 0; o < 3; ++o)
            #pragma unroll
            for (int m = 0; m < 2; ++m)
                a[o][m] = *(const half8*)&Crd[(o * 32 + m * 16 + lr) * LDA + ko];
        __builtin_amdgcn_s_setprio(1);
        #pragma unroll
        for (int o = 0; o < 3; ++o)
            #pragma unroll
            for (int m = 0; m < 2; ++m)
                acc[o][m] = MFMA16(a[o][m], b, acc[o][m]);
        __builtin_amdgcn_s_setprio(0);
    }
    #pragma unroll
    for (int o = 0; o < 3; ++o)
        #pragma unroll
        for (int m = 0; m < 2; ++m)
            #pragma unroll
            for (int r = 0; r < 4; ++r)
                Cwr[(o * 32 + m * 16 + kgrp * 4 + r) * LDA + col] =
                    (half_t)(acc[o][m][r] * gpre[m][r]);
    __syncthreads();
}

// ---------------- fully fused forward+backward, 32 samples / 16 waves ----------------
__global__ __launch_bounds__(1024, 1)
void netgrad_fused(const float* __restrict__ x,
                   const half_t* __restrict__ W1h, const float* __restrict__ b1,
                   const half_t* __restrict__ W2h, const float* __restrict__ b2,
                   const half_t* __restrict__ W3h, const float* __restrict__ b3,
                   const half_t* __restrict__ W4h, const float* __restrict__ b4,
                   const float* __restrict__ W5,
                   const half_t* __restrict__ T4h, const half_t* __restrict__ T3h,
                   const half_t* __restrict__ T2h, const half_t* __restrict__ T1h,
                   float* __restrict__ out)
{
    __shared__ half_t CA[96 * LDA];
    __shared__ half_t CB[96 * LDA];
    const int tid  = threadIdx.x;
    const int m0s  = blockIdx.x * 32;
    const int lane = tid & 63, lr = lane & 15, kgrp = lane >> 4;
    const int wn   = tid >> 6;             // wave = col span 0..15
    const int n0w  = wn * 16;

    float G1r[2][4], G2r[2][4], G3r[2][4], G4r[2][4];

    // ---- L1 (K=64): A straight from x; 2 sample-half frags, FN=1 ----
    {
        const int col = n0w + lr;
        half8 a[2][2];
        #pragma unroll
        for (int m = 0; m < 2; ++m)
            #pragma unroll
            for (int c2 = 0; c2 < 2; ++c2) {
                const float* xp = x + (size_t)(m0s + m * 16 + lr) * 64 + c2 * 32 + kgrp * 8;
                const float4 v0 = *(const float4*)xp;
                const float4 v1 = *(const float4*)(xp + 4);
                half8 t;
                t[0] = (half_t)v0.x; t[1] = (half_t)v0.y;
                t[2] = (half_t)v0.z; t[3] = (half_t)v0.w;
                t[4] = (half_t)v1.x; t[5] = (half_t)v1.y;
                t[6] = (half_t)v1.z; t[7] = (half_t)v1.w;
                a[m][c2] = t;
            }
        f32x4 acc[2] = {};
        #pragma unroll
        for (int c2 = 0; c2 < 2; ++c2) {
            const half8 b = *(const half8*)(W1h + (size_t)col * 64 + c2 * 32 + kgrp * 8);
            #pragma unroll
            for (int m = 0; m < 2; ++m)
                acc[m] = MFMA16(a[m][c2], b, acc[m]);
        }
        const float bc = b1[col];
        #pragma unroll
        for (int m = 0; m < 2; ++m)
            #pragma unroll
            for (int r = 0; r < 4; ++r) {
                const float pre = acc[m][r] + bc;
                float g, h;
                if (pre > 0.f) { g = 1.f; h = pre; }
                else           { g = __expf(pre); h = g - 1.f; }
                G1r[m][r] = g;
                CA[(m * 16 + kgrp * 4 + r) * LDA + col] = (half_t)h;
            }
        __syncthreads();
    }

    // ---- L2..L4: H ping-pong CA->CB->CA ----
    fwd_layer<true >(CA, CB, W2h, b2, G2r, n0w, lr, kgrp);
    fwd_layer<true >(CB, CA, W3h, b3, G3r, n0w, lr, kgrp);
    fwd_layer<false>(CA, nullptr, W4h, b4, G4r, n0w, lr, kgrp);

    // ---- expand into CB: CB[o*32+m*16+s][k] = W5[o][k] * G4[s][k] ----
    {
        const int k = n0w + lr;
        float w5v[3];
        #pragma unroll
        for (int o = 0; o < 3; ++o) w5v[o] = W5[o * 256 + k];
        #pragma unroll
        for (int o = 0; o < 3; ++o)
            #pragma unroll
            for (int m = 0; m < 2; ++m)
                #pragma unroll
                for (int r = 0; r < 4; ++r)
                    CB[(o * 32 + m * 16 + kgrp * 4 + r) * LDA + k] =
                        (half_t)(w5v[o] * G4r[m][r]);
        __syncthreads();
    }

    // ---- backward chain: CB -> CA -> CB -> CA ----
    bwd_mid(CB, CA, T4h, G3r, n0w, lr, kgrp);
    bwd_mid(CA, CB, T3h, G2r, n0w, lr, kgrp);
    bwd_mid(CB, CA, T2h, G1r, n0w, lr, kgrp);

    // ---- final: CA[96][256] @ T1h[64][256]^T -> out ----
    // 12 active waves: o = wn>>2 (0..2), j-group = wn&3; both m per wave.
    if (wn < 12) {
        const int o  = wn >> 2;
        const int j  = (wn & 3) * 16 + lr;
        const size_t bcf = (size_t)j * 256;
        f32x4 acc[2] = {};
        #pragma unroll
        for (int kc = 0; kc < 8; ++kc) {
            const int ko = kc * 32 + kgrp * 8;
            const half8 b = *(const half8*)(T1h + bcf + ko);
            #pragma unroll
            for (int m = 0; m < 2; ++m)
                acc[m] = MFMA16(*(const half8*)&CA[(o * 32 + m * 16 + lr) * LDA + ko],
                                b, acc[m]);
        }
        #pragma unroll
        for (int m = 0; m < 2; ++m)
            #pragma unroll
            for (int r = 0; r < 4; ++r)
                out[((size_t)(m0s + m * 16 + kgrp * 4 + r) * 3 + o) * 64 + j] = acc[m][r];
    }
}

extern "C" void kernel_launch(void* const* d_in, const int* in_sizes, int n_in,
                              void* d_out, int out_size, void* d_ws, size_t ws_size,
                              hipStream_t stream)
{
    const float* x  = (const float*)d_in[0];
    const float* W1 = (const float*)d_in[1];
    const float* b1 = (const float*)d_in[2];
    const float* W2 = (const float*)d_in[3];
    const float* b2 = (const float*)d_in[4];
    const float* W3 = (const float*)d_in[5];
    const float* b3 = (const float*)d_in[6];
    const float* W4 = (const float*)d_in[7];
    const float* b4 = (const float*)d_in[8];
    const float* W5 = (const float*)d_in[9];

    // ---- workspace carve (~0.9 MB f16 tables) ----
    char* p = (char*)d_ws;
    half_t* W1h = (half_t*)p; p += 256 * 64 * 2;
    half_t* T1h = (half_t*)p; p += 64 * 256 * 2;
    half_t* W2h = (half_t*)p; p += 256 * 256 * 2;
    half_t* T2h = (half_t*)p; p += 256 * 256 * 2;
    half_t* W3h = (half_t*)p; p += 256 * 256 * 2;
    half_t* T3h = (half_t*)p; p += 256 * 256 * 2;
    half_t* W4h = (half_t*)p; p += 256 * 256 * 2;
    half_t* T4h = (half_t*)p; p += 256 * 256 * 2;

    prep_split<<<208, 256, 0, stream>>>(W1, W2, W3, W4,
        W1h, T1h, W2h, T2h, W3h, T3h, W4h, T4h);

    netgrad_fused<<<Bsz / 32, 1024, 0, stream>>>(x,
        W1h, b1,  W2h, b2,  W3h, b3,  W4h, b4,
        W5,  T4h, T3h, T2h, T1h,
        (float*)d_out);
}

// Round 17
// 36.231 us; speedup vs baseline: 1.2489x; 1.2489x over previous
//
#include <hip/hip_runtime.h>
#include <cstdint>
#include <cstddef>

// NetGrad J = W5 D4 W4 D3 W3 D2 W2 D1 W1, output [B,3,64].
// r15 structure (32 samples/block, 8 waves col-split FN=2, 1 block/CU,
// permuted LDS columns, G1..G4 in regs) + FRAGMENT-MAJOR weight tables:
// each (col-block, kc) B-fragment stored as one contiguous 1 KB chunk so
// every weight load is a fully-coalesced wave-load (was: 16 x 64-B
// segments scattered at 512-B stride). k-permutation folded into prep.

typedef _Float16 half_t;
typedef __attribute__((ext_vector_type(2))) _Float16 half2v;
typedef __attribute__((ext_vector_type(8))) _Float16 half8;
typedef __attribute__((ext_vector_type(4))) float f32x4;

#define MFMA16(a, b, c) __builtin_amdgcn_mfma_f32_16x16x32_f16(a, b, c, 0, 0, 0)

constexpr int Bsz = 8192;
constexpr int LDA = 264;          // LDS row stride in halves (528 B)

// logical k at storage position p: p bits [7:5]=wn,[4:1]=lr,[0]=fn
//                                  k bits [7:5]=wn,[4]=fn,[3:0]=lr
__device__ __forceinline__ int kofp(int p) {
    return (p & 0xE0) | ((p & 1) << 4) | ((p >> 1) & 15);
}

// Fragment-major layout (K=256 tables): chunk (cb,kc) holds, contiguously,
// lane-ordered half8s: FQ[((cb*8+kc)*512) + lane*8 + e] = V[col=cb*16+(lane&15),
// p = kc*32 + (lane>>4)*8 + e, k = kofp(p)].

// ---------------- prep: gather-permute to fragment-major f16 tables ----------------
__global__ __launch_bounds__(256)
void prep(const float* __restrict__ W1, const float* __restrict__ W2,
          const float* __restrict__ W3, const float* __restrict__ W4,
          half_t* W1q, half_t* T1q,
          half_t* W2q, half_t* W3q, half_t* W4q,
          half_t* T2q, half_t* T3q, half_t* T4q)
{
    int idx = blockIdx.x * 256 + threadIdx.x;
    if (idx < 16384) {                 // W1q: K=64, linear k (cb, c2)
        const int cb = idx >> 10, c2 = (idx >> 9) & 1;
        const int lane = (idx >> 3) & 63, e = idx & 7;
        const int col = cb * 16 + (lane & 15);
        const int k = c2 * 32 + (lane >> 4) * 8 + e;
        W1q[idx] = (half_t)W1[col * 64 + k];
        return;
    }
    idx -= 16384;
    if (idx < 16384) {                 // T1q: 64 cols, K=256 permuted
        const int cb = idx >> 12, kc = (idx >> 9) & 7;
        const int lane = (idx >> 3) & 63, e = idx & 7;
        const int j = cb * 16 + (lane & 15);
        const int p = kc * 32 + (lane >> 4) * 8 + e;
        T1q[idx] = (half_t)W1[kofp(p) * 64 + j];
        return;
    }
    idx -= 16384;
    if (idx >= 6 * 65536) return;
    const int t = idx >> 16, i = idx & 65535;
    const int cb = i >> 12, kc = (i >> 9) & 7;
    const int lane = (i >> 3) & 63, e = i & 7;
    const int c = cb * 16 + (lane & 15);
    const int p = kc * 32 + (lane >> 4) * 8 + e;
    const int k = kofp(p);
    switch (t) {
        case 0: W2q[i] = (half_t)W2[c * 256 + k]; break;
        case 1: W3q[i] = (half_t)W3[c * 256 + k]; break;
        case 2: W4q[i] = (half_t)W4[c * 256 + k]; break;
        case 3: T2q[i] = (half_t)W2[k * 256 + c]; break;
        case 4: T3q[i] = (half_t)W3[k * 256 + c]; break;
        case 5: T4q[i] = (half_t)W4[k * 256 + c]; break;
    }
}

// ---------------- fwd layer (K=256): 2 A-frags (m), FN=2, coalesced B ----------------
template<bool WRITE_H>
__device__ __forceinline__
void fwd_layer_p(const half_t* __restrict__ Ard, half_t* __restrict__ Awr,
                 const half_t* __restrict__ Wq, const float* __restrict__ bias,
                 float gout[2][2][4], int n0w, int lr, int kgrp, int lane, int pb2)
{
    const int cb0 = n0w >> 4;
    f32x4 acc[2][2] = {};
    #pragma unroll
    for (int kc = 0; kc < 8; ++kc) {
        const int ko = kc * 32 + kgrp * 8;
        half8 b[2];
        #pragma unroll
        for (int fn = 0; fn < 2; ++fn)
            b[fn] = *(const half8*)(Wq + ((size_t)((cb0 + fn) * 8 + kc) << 9) + lane * 8);
        half8 a[2];
        #pragma unroll
        for (int m = 0; m < 2; ++m)
            a[m] = *(const half8*)&Ard[(m * 16 + lr) * LDA + ko];
        __builtin_amdgcn_s_setprio(1);
        #pragma unroll
        for (int fn = 0; fn < 2; ++fn)
            #pragma unroll
            for (int m = 0; m < 2; ++m)
                acc[m][fn] = MFMA16(a[m], b[fn], acc[m][fn]);
        __builtin_amdgcn_s_setprio(0);
    }
    float hv[2][4][2];
    #pragma unroll
    for (int fn = 0; fn < 2; ++fn) {
        const float bc = bias[n0w + fn * 16 + lr];
        #pragma unroll
        for (int m = 0; m < 2; ++m)
            #pragma unroll
            for (int r = 0; r < 4; ++r) {
                const float pre = acc[m][fn][r] + bc;
                float g, h;
                if (pre > 0.f) { g = 1.f; h = pre; }
                else           { g = __expf(pre); h = g - 1.f; }
                gout[m][fn][r] = g;
                hv[m][r][fn] = h;
            }
    }
    if constexpr (WRITE_H) {
        #pragma unroll
        for (int m = 0; m < 2; ++m)
            #pragma unroll
            for (int r = 0; r < 4; ++r) {
                half2v w = {(half_t)hv[m][r][0], (half_t)hv[m][r][1]};
                *(half2v*)&Awr[(m * 16 + kgrp * 4 + r) * LDA + pb2] = w;
            }
        __syncthreads();
    }
}

// ---------------- bwd mid step: 6 A-frags (3 o x 2 m), FN=2, coalesced B ----------------
__device__ __forceinline__
void bwd_mid(const half_t* __restrict__ Crd, half_t* __restrict__ Cwr,
             const half_t* __restrict__ Tq, const float gpre[2][2][4],
             int n0w, int lr, int kgrp, int lane, int pb2)
{
    const int cb0 = n0w >> 4;
    f32x4 acc[3][2][2] = {};
    #pragma unroll
    for (int kc = 0; kc < 8; ++kc) {
        const int ko = kc * 32 + kgrp * 8;
        half8 b[2];
        #pragma unroll
        for (int fn = 0; fn < 2; ++fn)
            b[fn] = *(const half8*)(Tq + ((size_t)((cb0 + fn) * 8 + kc) << 9) + lane * 8);
        half8 a[3][2];
        #pragma unroll
        for (int o = 0; o < 3; ++o)
            #pragma unroll
            for (int m = 0; m < 2; ++m)
                a[o][m] = *(const half8*)&Crd[(o * 32 + m * 16 + lr) * LDA + ko];
        __builtin_amdgcn_s_setprio(1);
        #pragma unroll
        for (int fn = 0; fn < 2; ++fn)
            #pragma unroll
            for (int o = 0; o < 3; ++o)
                #pragma unroll
                for (int m = 0; m < 2; ++m)
                    acc[o][m][fn] = MFMA16(a[o][m], b[fn], acc[o][m][fn]);
        __builtin_amdgcn_s_setprio(0);
    }
    #pragma unroll
    for (int o = 0; o < 3; ++o)
        #pragma unroll
        for (int m = 0; m < 2; ++m)
            #pragma unroll
            for (int r = 0; r < 4; ++r) {
                half2v w = {(half_t)(acc[o][m][0][r] * gpre[m][0][r]),
                            (half_t)(acc[o][m][1][r] * gpre[m][1][r])};
                *(half2v*)&Cwr[(o * 32 + m * 16 + kgrp * 4 + r) * LDA + pb2] = w;
            }
    __syncthreads();
}

// ---------------- fully fused forward+backward, 32 samples / 8 waves ----------------
__global__ __launch_bounds__(512, 1)
void netgrad_fused(const float* __restrict__ x,
                   const half_t* __restrict__ W1q, const float* __restrict__ b1,
                   const half_t* __restrict__ W2q, const float* __restrict__ b2,
                   const half_t* __restrict__ W3q, const float* __restrict__ b3,
                   const half_t* __restrict__ W4q, const float* __restrict__ b4,
                   const float* __restrict__ W5,
                   const half_t* __restrict__ T4q, const half_t* __restrict__ T3q,
                   const half_t* __restrict__ T2q, const half_t* __restrict__ T1q,
                   float* __restrict__ out)
{
    __shared__ half_t CA[96 * LDA];
    __shared__ half_t CB[96 * LDA];
    const int tid  = threadIdx.x;
    const int m0s  = blockIdx.x * 32;
    const int lane = tid & 63, lr = lane & 15, kgrp = lane >> 4;
    const int wn   = tid >> 6;             // wave = col span 0..7
    const int n0w  = wn * 32;
    const int pb2  = (wn << 5) | (lr << 1);   // permuted half2 write base

    float G1r[2][2][4], G2r[2][2][4], G3r[2][2][4], G4r[2][2][4];

    // ---- L1 (K=64): A straight from x; coalesced W1q fragments ----
    {
        const int cb0 = n0w >> 4;
        half8 a[2][2];
        #pragma unroll
        for (int m = 0; m < 2; ++m)
            #pragma unroll
            for (int c2 = 0; c2 < 2; ++c2) {
                const float* xp = x + (size_t)(m0s + m * 16 + lr) * 64 + c2 * 32 + kgrp * 8;
                const float4 v0 = *(const float4*)xp;
                const float4 v1 = *(const float4*)(xp + 4);
                half8 t;
                t[0] = (half_t)v0.x; t[1] = (half_t)v0.y;
                t[2] = (half_t)v0.z; t[3] = (half_t)v0.w;
                t[4] = (half_t)v1.x; t[5] = (half_t)v1.y;
                t[6] = (half_t)v1.z; t[7] = (half_t)v1.w;
                a[m][c2] = t;
            }
        f32x4 acc[2][2] = {};
        #pragma unroll
        for (int c2 = 0; c2 < 2; ++c2)
            #pragma unroll
            for (int fn = 0; fn < 2; ++fn) {
                const half8 b = *(const half8*)(W1q + ((size_t)((cb0 + fn) * 2 + c2) << 9) + lane * 8);
                #pragma unroll
                for (int m = 0; m < 2; ++m)
                    acc[m][fn] = MFMA16(a[m][c2], b, acc[m][fn]);
            }
        float hv[2][4][2];
        #pragma unroll
        for (int fn = 0; fn < 2; ++fn) {
            const float bc = b1[n0w + fn * 16 + lr];
            #pragma unroll
            for (int m = 0; m < 2; ++m)
                #pragma unroll
                for (int r = 0; r < 4; ++r) {
                    const float pre = acc[m][fn][r] + bc;
                    float g, h;
                    if (pre > 0.f) { g = 1.f; h = pre; }
                    else           { g = __expf(pre); h = g - 1.f; }
                    G1r[m][fn][r] = g;
                    hv[m][r][fn] = h;
                }
        }
        #pragma unroll
        for (int m = 0; m < 2; ++m)
            #pragma unroll
            for (int r = 0; r < 4; ++r) {
                half2v w = {(half_t)hv[m][r][0], (half_t)hv[m][r][1]};
                *(half2v*)&CA[(m * 16 + kgrp * 4 + r) * LDA + pb2] = w;
            }
        __syncthreads();
    }

    // ---- L2..L4: H ping-pong CA->CB->CA ----
    fwd_layer_p<true >(CA, CB, W2q, b2, G2r, n0w, lr, kgrp, lane, pb2);
    fwd_layer_p<true >(CB, CA, W3q, b3, G3r, n0w, lr, kgrp, lane, pb2);
    fwd_layer_p<false>(CA, nullptr, W4q, b4, G4r, n0w, lr, kgrp, lane, pb2);

    // ---- expand into CB: CB[o*32+s][k] = W5[o][k] * G4[s][k] ----
    {
        float w5v[3][2];
        #pragma unroll
        for (int fn = 0; fn < 2; ++fn) {
            const int k = n0w + fn * 16 + lr;
            #pragma unroll
            for (int o = 0; o < 3; ++o) w5v[o][fn] = W5[o * 256 + k];
        }
        #pragma unroll
        for (int o = 0; o < 3; ++o)
            #pragma unroll
            for (int m = 0; m < 2; ++m)
                #pragma unroll
                for (int r = 0; r < 4; ++r) {
                    half2v w = {(half_t)(w5v[o][0] * G4r[m][0][r]),
                                (half_t)(w5v[o][1] * G4r[m][1][r])};
                    *(half2v*)&CB[(o * 32 + m * 16 + kgrp * 4 + r) * LDA + pb2] = w;
                }
        __syncthreads();
    }

    // ---- backward chain: CB -> CA -> CB -> CA ----
    bwd_mid(CB, CA, T4q, G3r, n0w, lr, kgrp, lane, pb2);
    bwd_mid(CA, CB, T3q, G2r, n0w, lr, kgrp, lane, pb2);
    bwd_mid(CB, CA, T2q, G1r, n0w, lr, kgrp, lane, pb2);

    // ---- final: CA[96][256] @ T1q^T -> out ----
    // waves 0-3: o in {0,1}; waves 4-7: o=2. col-block cb = wn&3.
    {
        const int cb = wn & 3;
        const int j  = cb * 16 + lr;
        if (wn < 4) {
            f32x4 acc[2][2] = {};
            #pragma unroll
            for (int kc = 0; kc < 8; ++kc) {
                const int ko = kc * 32 + kgrp * 8;
                const half8 b = *(const half8*)(T1q + ((size_t)(cb * 8 + kc) << 9) + lane * 8);
                #pragma unroll
                for (int o = 0; o < 2; ++o)
                    #pragma unroll
                    for (int m = 0; m < 2; ++m)
                        acc[o][m] = MFMA16(*(const half8*)&CA[(o * 32 + m * 16 + lr) * LDA + ko],
                                           b, acc[o][m]);
            }
            #pragma unroll
            for (int o = 0; o < 2; ++o)
                #pragma unroll
                for (int m = 0; m < 2; ++m)
                    #pragma unroll
                    for (int r = 0; r < 4; ++r)
                        out[((size_t)(m0s + m * 16 + kgrp * 4 + r) * 3 + o) * 64 + j] = acc[o][m][r];
        } else {
            f32x4 acc[2] = {};
            #pragma unroll
            for (int kc = 0; kc < 8; ++kc) {
                const int ko = kc * 32 + kgrp * 8;
                const half8 b = *(const half8*)(T1q + ((size_t)(cb * 8 + kc) << 9) + lane * 8);
                #pragma unroll
                for (int m = 0; m < 2; ++m)
                    acc[m] = MFMA16(*(const half8*)&CA[(2 * 32 + m * 16 + lr) * LDA + ko],
                                    b, acc[m]);
            }
            #pragma unroll
            for (int m = 0; m < 2; ++m)
                #pragma unroll
                for (int r = 0; r < 4; ++r)
                    out[((size_t)(m0s + m * 16 + kgrp * 4 + r) * 3 + 2) * 64 + j] = acc[m][r];
        }
    }
}

extern "C" void kernel_launch(void* const* d_in, const int* in_sizes, int n_in,
                              void* d_out, int out_size, void* d_ws, size_t ws_size,
                              hipStream_t stream)
{
    const float* x  = (const float*)d_in[0];
    const float* W1 = (const float*)d_in[1];
    const float* b1 = (const float*)d_in[2];
    const float* W2 = (const float*)d_in[3];
    const float* b2 = (const float*)d_in[4];
    const float* W3 = (const float*)d_in[5];
    const float* b3 = (const float*)d_in[6];
    const float* W4 = (const float*)d_in[7];
    const float* b4 = (const float*)d_in[8];
    const float* W5 = (const float*)d_in[9];

    // ---- workspace carve (~0.9 MB f16 fragment-major tables) ----
    char* p = (char*)d_ws;
    half_t* W1q = (half_t*)p; p += 16384 * 2;
    half_t* T1q = (half_t*)p; p += 16384 * 2;
    half_t* W2q = (half_t*)p; p += 65536 * 2;
    half_t* W3q = (half_t*)p; p += 65536 * 2;
    half_t* W4q = (half_t*)p; p += 65536 * 2;
    half_t* T2q = (half_t*)p; p += 65536 * 2;
    half_t* T3q = (half_t*)p; p += 65536 * 2;
    half_t* T4q = (half_t*)p; p += 65536 * 2;

    const int prep_elems = 16384 + 16384 + 6 * 65536;
    prep<<<(prep_elems + 255) / 256, 256, 0, stream>>>(W1, W2, W3, W4,
        W1q, T1q, W2q, W3q, W4q, T2q, T3q, T4q);

    netgrad_fused<<<Bsz / 32, 512, 0, stream>>>(x,
        W1q, b1,  W2q, b2,  W3q, b3,  W4q, b4,
        W5,  T4q, T3q, T2q, T1q,
        (float*)d_out);
}

// Round 18
// 29.390 us; speedup vs baseline: 1.5396x; 1.2328x over previous
//
#include <hip/hip_runtime.h>
#include <cstdint>
#include <cstddef>

// NetGrad J = W5 D4 W4 D3 W3 D2 W2 D1 W1, output [B,3,64].
// r17 structure (32 samples/block, 8 waves col-split FN=2, 1 block/CU,
// fragment-major coalesced weight tables, permuted LDS columns)
// + CROSS-PHASE B PREFETCH: two 16-frag register buffers (BA/BB) alternate;
// next phase's table loads issue at the top of the current phase (the loads
// depend on nothing), hiding L2 latency under current-phase compute.
// Feasible now because launch_bounds(512,1) gives a 256-VGPR budget
// (r6/r7 prefetch failed under the (512,4) 128-VGPR cap).
// G1..G3 persisted as packed half2v (24 VGPRs instead of 64).

typedef _Float16 half_t;
typedef __attribute__((ext_vector_type(2))) _Float16 half2v;
typedef __attribute__((ext_vector_type(8))) _Float16 half8;
typedef __attribute__((ext_vector_type(4))) float f32x4;

#define MFMA16(a, b, c) __builtin_amdgcn_mfma_f32_16x16x32_f16(a, b, c, 0, 0, 0)

constexpr int Bsz = 8192;
constexpr int LDA = 264;          // LDS row stride in halves (528 B)

// logical k at storage position p: p bits [7:5]=wn,[4:1]=lr,[0]=fn
__device__ __forceinline__ int kofp(int p) {
    return (p & 0xE0) | ((p & 1) << 4) | ((p >> 1) & 15);
}

// ---------------- prep: gather-permute to fragment-major f16 tables ----------------
__global__ __launch_bounds__(256)
void prep(const float* __restrict__ W1, const float* __restrict__ W2,
          const float* __restrict__ W3, const float* __restrict__ W4,
          half_t* W1q, half_t* T1q,
          half_t* W2q, half_t* W3q, half_t* W4q,
          half_t* T2q, half_t* T3q, half_t* T4q)
{
    int idx = blockIdx.x * 256 + threadIdx.x;
    if (idx < 16384) {                 // W1q: K=64, linear k (cb, c2)
        const int cb = idx >> 10, c2 = (idx >> 9) & 1;
        const int lane = (idx >> 3) & 63, e = idx & 7;
        const int col = cb * 16 + (lane & 15);
        const int k = c2 * 32 + (lane >> 4) * 8 + e;
        W1q[idx] = (half_t)W1[col * 64 + k];
        return;
    }
    idx -= 16384;
    if (idx < 16384) {                 // T1q: 64 cols, K=256 permuted
        const int cb = idx >> 12, kc = (idx >> 9) & 7;
        const int lane = (idx >> 3) & 63, e = idx & 7;
        const int j = cb * 16 + (lane & 15);
        const int p = kc * 32 + (lane >> 4) * 8 + e;
        T1q[idx] = (half_t)W1[kofp(p) * 64 + j];
        return;
    }
    idx -= 16384;
    if (idx >= 6 * 65536) return;
    const int t = idx >> 16, i = idx & 65535;
    const int cb = i >> 12, kc = (i >> 9) & 7;
    const int lane = (i >> 3) & 63, e = i & 7;
    const int c = cb * 16 + (lane & 15);
    const int p = kc * 32 + (lane >> 4) * 8 + e;
    const int k = kofp(p);
    switch (t) {
        case 0: W2q[i] = (half_t)W2[c * 256 + k]; break;
        case 1: W3q[i] = (half_t)W3[c * 256 + k]; break;
        case 2: W4q[i] = (half_t)W4[c * 256 + k]; break;
        case 3: T2q[i] = (half_t)W2[k * 256 + c]; break;
        case 4: T3q[i] = (half_t)W3[k * 256 + c]; break;
        case 5: T4q[i] = (half_t)W4[k * 256 + c]; break;
    }
}

// ---------------- prefetch helpers (coalesced fragment-major loads) ----------------
__device__ __forceinline__
void loadB16(half8 (&B)[16], const half_t* __restrict__ Tq, int cb0, int lane)
{
    #pragma unroll
    for (int fn = 0; fn < 2; ++fn)
        #pragma unroll
        for (int kc = 0; kc < 8; ++kc)
            B[fn * 8 + kc] = *(const half8*)(Tq + ((size_t)((cb0 + fn) * 8 + kc) << 9) + lane * 8);
}

__device__ __forceinline__
void loadB8(half8 (&B)[16], const half_t* __restrict__ Tq, int cb, int lane)
{
    #pragma unroll
    for (int kc = 0; kc < 8; ++kc)
        B[kc] = *(const half8*)(Tq + ((size_t)(cb * 8 + kc) << 9) + lane * 8);
}

// ---------------- fwd phase: preloaded B; G packed half2v; H' -> Awr ----------------
template<bool WRITE_H>
__device__ __forceinline__
void fwd_phase(const half8 (&B)[16],
               const half_t* __restrict__ Ard, half_t* __restrict__ Awr,
               const float* __restrict__ bias, half2v gout[2][4],
               int n0w, int lr, int kgrp, int pb2)
{
    const float bc0 = bias[n0w + lr];
    const float bc1 = bias[n0w + 16 + lr];
    f32x4 acc[2][2] = {};
    #pragma unroll
    for (int kc = 0; kc < 8; ++kc) {
        const int ko = kc * 32 + kgrp * 8;
        half8 a[2];
        #pragma unroll
        for (int m = 0; m < 2; ++m)
            a[m] = *(const half8*)&Ard[(m * 16 + lr) * LDA + ko];
        __builtin_amdgcn_s_setprio(1);
        #pragma unroll
        for (int fn = 0; fn < 2; ++fn)
            #pragma unroll
            for (int m = 0; m < 2; ++m)
                acc[m][fn] = MFMA16(a[m], B[fn * 8 + kc], acc[m][fn]);
        __builtin_amdgcn_s_setprio(0);
    }
    #pragma unroll
    for (int m = 0; m < 2; ++m)
        #pragma unroll
        for (int r = 0; r < 4; ++r) {
            float g[2], h[2];
            #pragma unroll
            for (int fn = 0; fn < 2; ++fn) {
                const float pre = acc[m][fn][r] + (fn ? bc1 : bc0);
                if (pre > 0.f) { g[fn] = 1.f; h[fn] = pre; }
                else           { g[fn] = __expf(pre); h[fn] = g[fn] - 1.f; }
            }
            gout[m][r] = half2v{(half_t)g[0], (half_t)g[1]};
            if constexpr (WRITE_H) {
                half2v w = {(half_t)h[0], (half_t)h[1]};
                *(half2v*)&Awr[(m * 16 + kgrp * 4 + r) * LDA + pb2] = w;
            }
        }
    if constexpr (WRITE_H)
        __syncthreads();
}

// ---------------- bwd phase: preloaded B; 6 A-frags; G from packed half2v ----------------
__device__ __forceinline__
void bwd_phase(const half8 (&B)[16],
               const half_t* __restrict__ Crd, half_t* __restrict__ Cwr,
               const half2v gpre[2][4], int lr, int kgrp, int pb2)
{
    f32x4 acc[3][2][2] = {};
    #pragma unroll
    for (int kc = 0; kc < 8; ++kc) {
        const int ko = kc * 32 + kgrp * 8;
        half8 a[3][2];
        #pragma unroll
        for (int o = 0; o < 3; ++o)
            #pragma unroll
            for (int m = 0; m < 2; ++m)
                a[o][m] = *(const half8*)&Crd[(o * 32 + m * 16 + lr) * LDA + ko];
        __builtin_amdgcn_s_setprio(1);
        #pragma unroll
        for (int fn = 0; fn < 2; ++fn)
            #pragma unroll
            for (int o = 0; o < 3; ++o)
                #pragma unroll
                for (int m = 0; m < 2; ++m)
                    acc[o][m][fn] = MFMA16(a[o][m], B[fn * 8 + kc], acc[o][m][fn]);
        __builtin_amdgcn_s_setprio(0);
    }
    #pragma unroll
    for (int o = 0; o < 3; ++o)
        #pragma unroll
        for (int m = 0; m < 2; ++m)
            #pragma unroll
            for (int r = 0; r < 4; ++r) {
                const float g0 = (float)gpre[m][r][0];
                const float g1 = (float)gpre[m][r][1];
                half2v w = {(half_t)(acc[o][m][0][r] * g0),
                            (half_t)(acc[o][m][1][r] * g1)};
                *(half2v*)&Cwr[(o * 32 + m * 16 + kgrp * 4 + r) * LDA + pb2] = w;
            }
    __syncthreads();
}

// ---------------- fully fused forward+backward, 32 samples / 8 waves ----------------
__global__ __launch_bounds__(512, 1)
void netgrad_fused(const float* __restrict__ x,
                   const half_t* __restrict__ W1q, const float* __restrict__ b1,
                   const half_t* __restrict__ W2q, const float* __restrict__ b2,
                   const half_t* __restrict__ W3q, const float* __restrict__ b3,
                   const half_t* __restrict__ W4q, const float* __restrict__ b4,
                   const float* __restrict__ W5,
                   const half_t* __restrict__ T4q, const half_t* __restrict__ T3q,
                   const half_t* __restrict__ T2q, const half_t* __restrict__ T1q,
                   float* __restrict__ out)
{
    __shared__ half_t CA[96 * LDA];
    __shared__ half_t CB[96 * LDA];
    const int tid  = threadIdx.x;
    const int m0s  = blockIdx.x * 32;
    const int lane = tid & 63, lr = lane & 15, kgrp = lane >> 4;
    const int wn   = tid >> 6;             // wave = col span 0..7
    const int n0w  = wn * 32;
    const int cb0  = wn * 2;
    const int pb2  = (wn << 5) | (lr << 1);

    half8 BA[16], BB[16];
    half2v G1p[2][4], G2p[2][4], G3p[2][4];

    // ---- L1 (K=64) + prologue prefetch of W2 into BA ----
    {
        half8 a[2][2];
        #pragma unroll
        for (int m = 0; m < 2; ++m)
            #pragma unroll
            for (int c2 = 0; c2 < 2; ++c2) {
                const float* xp = x + (size_t)(m0s + m * 16 + lr) * 64 + c2 * 32 + kgrp * 8;
                const float4 v0 = *(const float4*)xp;
                const float4 v1 = *(const float4*)(xp + 4);
                half8 t;
                t[0] = (half_t)v0.x; t[1] = (half_t)v0.y;
                t[2] = (half_t)v0.z; t[3] = (half_t)v0.w;
                t[4] = (half_t)v1.x; t[5] = (half_t)v1.y;
                t[6] = (half_t)v1.z; t[7] = (half_t)v1.w;
                a[m][c2] = t;
            }
        half8 w1[2][2];
        #pragma unroll
        for (int fn = 0; fn < 2; ++fn)
            #pragma unroll
            for (int c2 = 0; c2 < 2; ++c2)
                w1[fn][c2] = *(const half8*)(W1q + ((size_t)((cb0 + fn) * 2 + c2) << 9) + lane * 8);
        loadB16(BA, W2q, cb0, lane);       // prefetch L2 weights

        f32x4 acc[2][2] = {};
        #pragma unroll
        for (int c2 = 0; c2 < 2; ++c2)
            #pragma unroll
            for (int fn = 0; fn < 2; ++fn)
                #pragma unroll
                for (int m = 0; m < 2; ++m)
                    acc[m][fn] = MFMA16(a[m][c2], w1[fn][c2], acc[m][fn]);
        const float bc0 = b1[n0w + lr];
        const float bc1 = b1[n0w + 16 + lr];
        #pragma unroll
        for (int m = 0; m < 2; ++m)
            #pragma unroll
            for (int r = 0; r < 4; ++r) {
                float g[2], h[2];
                #pragma unroll
                for (int fn = 0; fn < 2; ++fn) {
                    const float pre = acc[m][fn][r] + (fn ? bc1 : bc0);
                    if (pre > 0.f) { g[fn] = 1.f; h[fn] = pre; }
                    else           { g[fn] = __expf(pre); h[fn] = g[fn] - 1.f; }
                }
                G1p[m][r] = half2v{(half_t)g[0], (half_t)g[1]};
                half2v w = {(half_t)h[0], (half_t)h[1]};
                *(half2v*)&CA[(m * 16 + kgrp * 4 + r) * LDA + pb2] = w;
            }
        __syncthreads();
    }

    // ---- L2..L4 with rolling prefetch ----
    loadB16(BB, W3q, cb0, lane);
    fwd_phase<true >(BA, CA, CB, b2, G2p, n0w, lr, kgrp, pb2);
    loadB16(BA, W4q, cb0, lane);
    fwd_phase<true >(BB, CB, CA, b3, G3p, n0w, lr, kgrp, pb2);
    loadB16(BB, T4q, cb0, lane);

    // ---- L4 + expand (no H write; expand into CB) ----
    {
        half2v G4p[2][4];
        fwd_phase<false>(BA, CA, nullptr, b4, G4p, n0w, lr, kgrp, pb2);
        float w5v[3][2];
        #pragma unroll
        for (int fn = 0; fn < 2; ++fn) {
            const int k = n0w + fn * 16 + lr;
            #pragma unroll
            for (int o = 0; o < 3; ++o) w5v[o][fn] = W5[o * 256 + k];
        }
        #pragma unroll
        for (int o = 0; o < 3; ++o)
            #pragma unroll
            for (int m = 0; m < 2; ++m)
                #pragma unroll
                for (int r = 0; r < 4; ++r) {
                    half2v w = {(half_t)(w5v[o][0] * (float)G4p[m][r][0]),
                                (half_t)(w5v[o][1] * (float)G4p[m][r][1])};
                    *(half2v*)&CB[(o * 32 + m * 16 + kgrp * 4 + r) * LDA + pb2] = w;
                }
        __syncthreads();
    }

    // ---- backward chain with rolling prefetch: CB -> CA -> CB -> CA ----
    loadB16(BA, T3q, cb0, lane);
    bwd_phase(BB, CB, CA, G3p, lr, kgrp, pb2);
    loadB16(BB, T2q, cb0, lane);
    bwd_phase(BA, CA, CB, G2p, lr, kgrp, pb2);
    loadB8 (BA, T1q, wn & 3, lane);        // final-phase T1 frags (8)
    bwd_phase(BB, CB, CA, G1p, lr, kgrp, pb2);

    // ---- final: CA[96][256] @ T1q^T -> out (B from BA[0..7]) ----
    {
        const int j = (wn & 3) * 16 + lr;
        if (wn < 4) {
            f32x4 acc[2][2] = {};
            #pragma unroll
            for (int kc = 0; kc < 8; ++kc) {
                const int ko = kc * 32 + kgrp * 8;
                #pragma unroll
                for (int o = 0; o < 2; ++o)
                    #pragma unroll
                    for (int m = 0; m < 2; ++m)
                        acc[o][m] = MFMA16(*(const half8*)&CA[(o * 32 + m * 16 + lr) * LDA + ko],
                                           BA[kc], acc[o][m]);
            }
            #pragma unroll
            for (int o = 0; o < 2; ++o)
                #pragma unroll
                for (int m = 0; m < 2; ++m)
                    #pragma unroll
                    for (int r = 0; r < 4; ++r)
                        out[((size_t)(m0s + m * 16 + kgrp * 4 + r) * 3 + o) * 64 + j] = acc[o][m][r];
        } else {
            f32x4 acc[2] = {};
            #pragma unroll
            for (int kc = 0; kc < 8; ++kc) {
                const int ko = kc * 32 + kgrp * 8;
                #pragma unroll
                for (int m = 0; m < 2; ++m)
                    acc[m] = MFMA16(*(const half8*)&CA[(2 * 32 + m * 16 + lr) * LDA + ko],
                                    BA[kc], acc[m]);
            }
            #pragma unroll
            for (int m = 0; m < 2; ++m)
                #pragma unroll
                for (int r = 0; r < 4; ++r)
                    out[((size_t)(m0s + m * 16 + kgrp * 4 + r) * 3 + 2) * 64 + j] = acc[m][r];
        }
    }
}

extern "C" void kernel_launch(void* const* d_in, const int* in_sizes, int n_in,
                              void* d_out, int out_size, void* d_ws, size_t ws_size,
                              hipStream_t stream)
{
    const float* x  = (const float*)d_in[0];
    const float* W1 = (const float*)d_in[1];
    const float* b1 = (const float*)d_in[2];
    const float* W2 = (const float*)d_in[3];
    const float* b2 = (const float*)d_in[4];
    const float* W3 = (const float*)d_in[5];
    const float* b3 = (const float*)d_in[6];
    const float* W4 = (const float*)d_in[7];
    const float* b4 = (const float*)d_in[8];
    const float* W5 = (const float*)d_in[9];

    // ---- workspace carve (~0.9 MB f16 fragment-major tables) ----
    char* p = (char*)d_ws;
    half_t* W1q = (half_t*)p; p += 16384 * 2;
    half_t* T1q = (half_t*)p; p += 16384 * 2;
    half_t* W2q = (half_t*)p; p += 65536 * 2;
    half_t* W3q = (half_t*)p; p += 65536 * 2;
    half_t* W4q = (half_t*)p; p += 65536 * 2;
    half_t* T2q = (half_t*)p; p += 65536 * 2;
    half_t* T3q = (half_t*)p; p += 65536 * 2;
    half_t* T4q = (half_t*)p; p += 65536 * 2;

    const int prep_elems = 16384 + 16384 + 6 * 65536;
    prep<<<(prep_elems + 255) / 256, 256, 0, stream>>>(W1, W2, W3, W4,
        W1q, T1q, W2q, W3q, W4q, T2q, T3q, T4q);

    netgrad_fused<<<Bsz / 32, 512, 0, stream>>>(x,
        W1q, b1,  W2q, b2,  W3q, b3,  W4q, b4,
        W5,  T4q, T3q, T2q, T1q,
        (float*)d_out);
}